// Round 4
// baseline (287.981 us; speedup 1.0000x reference)
//
#include <hip/hip_runtime.h>
#include <hip/hip_cooperative_groups.h>
#include <math.h>

// TwoBranchDH_SFNN: B=128, T=2048, H=512, D_IN=40, D_OUT=1
//
// R15 = R14 + two measured fixes:
//  1) fir phase was LDS-BW-bound (2040 window dwords/thread ~= 100k LDS
//     cyc/CU > 61k FMA cyc). New mapping: thread = (lg: 8 slices of 24
//     lags) x (og: 64 groups of 8 outputs) -> 31 window dwords per 192
//     FMA (1.65x less LDS traffic), balancing LDS and VALU pipes.
//     Layout phi(t) = t + (t>>3), row stride 792: lane pitch 9 dwords,
//     gcd(9,32)=1 -> 2 lanes/bank (free).
//  2) ~25us per extra serialized launch (R11..R14 consistent). Prep is
//     fused via cooperative launch + grid sync (512 blocks x 512 thr,
//     63.4KB LDS -> exactly 2 blocks/CU x 256 CU co-resident). Fallback
//     to two plain launches (mode arg) if cooperative launch fails.
//
// out[b,t] = sigmoid( sum_{s<192,d} g[s,d]*x[b,t-s,d] + c(t) ), f32 only.

#define B_   128
#define T_   2048
#define DIN  40
#define L_   192
#define TT   704             // 512 + 192 staged t-window
#define RS2  792             // phi-padded row stride (dwords)

__device__ float d_gT[DIN * L_];     // [d][s]
__device__ float d_c[T_];            // bias transient + bo

__device__ __forceinline__ float sigmf(float v) { return 1.f / (1.f + __expf(-v)); }

// mode 0: prep + grid.sync + FIR (cooperative)
// mode 1: prep only (plain launch, grid 104)
// mode 2: FIR only (plain launch, grid 512)
__global__ __launch_bounds__(512, 4) void sfnn_fused(
    const float* __restrict__ x,
    const float* __restrict__ W1, const float* __restrict__ b1v,
    const float* __restrict__ W2, const float* __restrict__ b2v,
    const float* __restrict__ Wo, const float* __restrict__ bo,
    const float* __restrict__ tau_m, const float* __restrict__ tau_n1,
    const float* __restrict__ tau_n2,
    float* __restrict__ out, int mode)
{
    __shared__ __align__(16) float xw[20 * RS2];   // 63360 B -> 2 blocks/CU

    const int blk = blockIdx.x;
    const int tid = threadIdx.x;

    // ---------------- prep (blocks 0..103) ----------------
    if (mode != 2) {
        if (blk < 40) {
            // g[d][s] = sum_h Wo*(1-a)(1-b)*(a^{s+1}-b^{s+1})/(a-b)*W[h,dm]
            float* cw  = xw;
            float* laG = xw + 512;
            float* lbG = xw + 1024;
            const int d = blk, dm = (d < 20) ? d : d - 20;
            {
                const int h = tid;
                const float a = sigmf(tau_m[h]);
                float bb = sigmf((d < 20) ? tau_n1[h] : tau_n2[h]);
                float diff = a - bb;
                if (fabsf(diff) < 1e-5f) { bb = a - 1e-5f; diff = 1e-5f; }
                const float w = (d < 20) ? W1[h * 20 + dm] : W2[h * 20 + dm];
                cw[h]  = Wo[h] * (1.f - a) * (1.f - bb) * w / diff;
                laG[h] = log2f(a);
                lbG[h] = log2f(bb);
            }
            __syncthreads();
            if (tid < 192) {
                const float fs1 = (float)(tid + 1);
                float acc = 0.f;
                for (int h = 0; h < 512; ++h)
                    acc += cw[h] * (exp2f(fs1 * laG[h]) - exp2f(fs1 * lbG[h]));
                d_gT[d * L_ + tid] = acc;
            }
        } else if (blk < 104) {
            // c(t) = bo + sum_h [cst - A*a^{t+1} + B1*b1^{t+1} + B2*b2^{t+1}]
            float* As   = xw;
            float* B1s  = xw + 512;
            float* B2s  = xw + 1024;
            float* cst  = xw + 1536;
            float* laC  = xw + 2048;
            float* lb1C = xw + 2560;
            float* lb2C = xw + 3072;
            float* red  = xw + 3584;              // [16][32]
            {
                const int h = tid;
                const float a = sigmf(tau_m[h]);
                float b1c = sigmf(tau_n1[h]); float dd1 = a - b1c;
                if (fabsf(dd1) < 1e-5f) { b1c = a - 1e-5f; dd1 = 1e-5f; }
                float b2c = sigmf(tau_n2[h]); float dd2 = a - b2c;
                if (fabsf(dd2) < 1e-5f) { b2c = a - 1e-5f; dd2 = 1e-5f; }
                const float wv = Wo[h], bb1 = b1v[h], bb2 = b2v[h];
                As[h]  = wv * (bb1 * a * (1.f - b1c) / dd1
                             + bb2 * a * (1.f - b2c) / dd2);
                B1s[h] = wv * bb1 * b1c * (1.f - a) / dd1;
                B2s[h] = wv * bb2 * b2c * (1.f - a) / dd2;
                cst[h] = wv * (bb1 + bb2);
                laC[h] = log2f(a); lb1C[h] = log2f(b1c); lb2C[h] = log2f(b2c);
            }
            __syncthreads();
            const int tl = tid & 31, hc = tid >> 5;
            const float ft1 = (float)((blk - 40) * 32 + tl + 1);
            float acc = 0.f;
            for (int hh = 0; hh < 32; ++hh) {
                const int h2 = hc * 32 + hh;
                acc += cst[h2] - As[h2] * exp2f(ft1 * laC[h2])
                     + B1s[h2] * exp2f(ft1 * lb1C[h2])
                     + B2s[h2] * exp2f(ft1 * lb2C[h2]);
            }
            red[hc * 32 + tl] = acc;
            __syncthreads();
            if (tid < 32) {
                float s = bo[0];
#pragma unroll
                for (int c = 0; c < 16; ++c) s += red[c * 32 + tid];
                d_c[(blk - 40) * 32 + tid] = s;
            }
        }
        if (mode == 1) return;
        __threadfence();                          // publish d_gT / d_c
        cooperative_groups::this_grid().sync();
        __syncthreads();                          // xw safe to reuse
    }

    // ---------------- FIR ----------------
    // thread: outputs t0+8*og+{0..7}, lags [24*lg, 24*lg+24)
    const int b   = blk >> 2;
    const int t0  = (blk & 3) << 9;
    const int og  = tid & 63;
    const int lg  = tid >> 6;                     // == wave id (uniform)
    const int lg_u = __builtin_amdgcn_readfirstlane(lg);

    const float* __restrict__ xb = x + (size_t)b * (T_ * DIN);

    float y[8];
#pragma unroll
    for (int r = 0; r < 8; ++r) y[r] = 0.f;

    // logical window base A0 = 8*og + 169 - 24*lg = 8K+1; phi(A0) = 9K+1
    const int K  = og + 21 - 3 * lg;
    const int AQ = 9 * K + 1;

    for (int dh = 0; dh < 2; ++dh) {
        __syncthreads();   // previous-phase readers done before overwrite
        // stage x[t0-192 .. t0+512) x d in [20dh,20dh+20) -> xw[dl][phi(tt)]
        for (int k = 0; k < 7; ++k) {
            const int phi = tid + 512 * k;
            if (phi < TT * 5) {
                const int tr = phi / 5, dq = phi - tr * 5;
                const int tg = t0 - L_ + tr;
                float4 v = make_float4(0.f, 0.f, 0.f, 0.f);
                if (tg >= 0)
                    v = *(const float4*)&xb[tg * DIN + dh * 20 + dq * 4];
                const int tph = tr + (tr >> 3);
                float* colp = &xw[(dq * 4) * RS2 + tph];
                colp[0]       = v.x;
                colp[RS2]     = v.y;
                colp[2 * RS2] = v.z;
                colp[3 * RS2] = v.w;
            }
        }
        __syncthreads();

        for (int dl = 0; dl < 20; ++dl) {
            const float* __restrict__ rowp = &xw[dl * RS2 + AQ];
            const float* __restrict__ gr = &d_gT[(dh * 20 + dl) * L_ + 24 * lg_u];
            float W[31];
#pragma unroll
            for (int m = 0; m < 31; ++m)
                W[m] = rowp[m + ((m + 1) >> 3)];  // imm offsets, lane pitch 9
#pragma unroll
            for (int j = 0; j < 24; ++j) {
                const float gj = gr[j];           // wave-uniform -> s_load
#pragma unroll
                for (int r = 0; r < 8; ++r)
                    y[r] = fmaf(gj, W[r + 23 - j], y[r]);
            }
        }
    }

    // reduce 8 lag-slice partials per output
    __syncthreads();
    if (lg > 0) {
        float* p = &xw[((lg - 1) * 64 + og) * 12];
        *(float4*)&p[0] = make_float4(y[0], y[1], y[2], y[3]);
        *(float4*)&p[4] = make_float4(y[4], y[5], y[6], y[7]);
    }
    __syncthreads();
    if (lg == 0) {
#pragma unroll
        for (int pw = 0; pw < 7; ++pw) {
            const float* p = &xw[(pw * 64 + og) * 12];
            float4 u0 = *(const float4*)&p[0];
            float4 u1 = *(const float4*)&p[4];
            y[0] += u0.x; y[1] += u0.y; y[2] += u0.z; y[3] += u0.w;
            y[4] += u1.x; y[5] += u1.y; y[6] += u1.z; y[7] += u1.w;
        }
        const float4 c0 = *(const float4*)&d_c[t0 + 8 * og];
        const float4 c1 = *(const float4*)&d_c[t0 + 8 * og + 4];
        float4 o0, o1;
        o0.x = sigmf(y[0] + c0.x); o0.y = sigmf(y[1] + c0.y);
        o0.z = sigmf(y[2] + c0.z); o0.w = sigmf(y[3] + c0.w);
        o1.x = sigmf(y[4] + c1.x); o1.y = sigmf(y[5] + c1.y);
        o1.z = sigmf(y[6] + c1.z); o1.w = sigmf(y[7] + c1.w);
        float* op = out + (size_t)b * T_ + t0 + 8 * og;
        *(float4*)&op[0] = o0;
        *(float4*)&op[4] = o1;
    }
}

extern "C" void kernel_launch(void* const* d_in, const int* in_sizes, int n_in,
                              void* d_out, int out_size, void* d_ws, size_t ws_size,
                              hipStream_t stream)
{
    const float* x      = (const float*)d_in[0];
    const float* W1     = (const float*)d_in[1];
    const float* b1     = (const float*)d_in[2];
    const float* W2     = (const float*)d_in[3];
    const float* b2     = (const float*)d_in[4];
    const float* Wo     = (const float*)d_in[5];
    const float* bo     = (const float*)d_in[6];
    const float* tau_m  = (const float*)d_in[7];
    const float* tau_n1 = (const float*)d_in[8];
    const float* tau_n2 = (const float*)d_in[9];
    float* outp = (float*)d_out;

    int mode0 = 0;
    void* args[12] = {
        (void*)&x, (void*)&W1, (void*)&b1, (void*)&W2, (void*)&b2,
        (void*)&Wo, (void*)&bo, (void*)&tau_m, (void*)&tau_n1, (void*)&tau_n2,
        (void*)&outp, (void*)&mode0
    };
    hipError_t e = hipLaunchCooperativeKernel((const void*)sfnn_fused,
                                              dim3(512), dim3(512),
                                              args, 0, stream);
    if (e != hipSuccess) {
        // fallback: two plain launches (prep, then FIR)
        hipLaunchKernelGGL(sfnn_fused, dim3(104), dim3(512), 0, stream,
                           x, W1, b1, W2, b2, Wo, bo, tau_m, tau_n1, tau_n2,
                           outp, 1);
        hipLaunchKernelGGL(sfnn_fused, dim3(512), dim3(512), 0, stream,
                           x, W1, b1, W2, b2, Wo, bo, tau_m, tau_n1, tau_n2,
                           outp, 2);
    }
}

// Round 5
// 162.191 us; speedup vs baseline: 1.7756x; 1.7756x over previous
//
#include <hip/hip_runtime.h>
#include <math.h>

// TwoBranchDH_SFNN: B=128, T=2048, H=512, D_IN=40, D_OUT=1
//
// R16 = de-confounded R15. R15's 181us FIR regression was diagnosed as
// scratch spill (WRITE_SIZE 1.0->5.2MB, FETCH +3MB, VALUBusy 50->21%) from
// the 64-VGPR cap of __launch_bounds__(512,4) + cooperative-path compile,
// NOT the new thread mapping. R16 keeps:
//  - R14's proven prepG (verified math, separate launch),
//  - R15's 24-lag x 8-output mapping (620 LDS read2/thread vs R14's 1020;
//    the FIR is LDS-instruction-rate-bound at ~6.5cyc/read2),
//  - phi(t) = t + (t>>3) layout, lane pitch 9 dwords -> 2 lanes/bank,
// and changes:
//  - standalone FIR kernel, no mode arg, no cooperative machinery,
//  - __launch_bounds__(512,2): VGPR cap 128 (no spill; 4 waves/SIMD and
//    2 blocks/CU still hold -- LDS 63.5KB is the binding constraint),
//  - RS2 792->794: staging-write dq-collision (4*RS2 mod 32==0) fixed.
//
// out[b,t] = sigmoid( sum_{s<192,d} g[s,d]*x[b,t-s,d] + c(t) ), f32 only.

#define B_   128
#define T_   2048
#define DIN  40
#define L_   192
#define TT   704             // 512 + 192 staged t-window
#define RS2  794             // phi-padded row stride (dwords); phi(703)=790

__device__ float d_gT[DIN * L_];     // [d][s]
__device__ float d_c[T_];            // bias transient + bo

__device__ __forceinline__ float sigmf(float v) { return 1.f / (1.f + __expf(-v)); }

// ---------------- prepG: g (blocks 0..39) + c(t) (blocks 40..103) --------
__global__ __launch_bounds__(256) void prepG(
    const float* __restrict__ W1, const float* __restrict__ b1v,
    const float* __restrict__ W2, const float* __restrict__ b2v,
    const float* __restrict__ Wo, const float* __restrict__ bo,
    const float* __restrict__ tau_m, const float* __restrict__ tau_n1,
    const float* __restrict__ tau_n2)
{
    const int blk = blockIdx.x, tid = threadIdx.x;
    if (blk < 40) {
        // g[d][s] = sum_h Wo*(1-a)(1-b)*(a^{s+1}-b^{s+1})/(a-b)*W[h,dm]
        __shared__ float cw[512], laG[512], lbG[512];
        const int d = blk;
        const int dm = (d < 20) ? d : d - 20;
        for (int i = 0; i < 2; ++i) {
            const int h = tid + 256 * i;
            const float a = sigmf(tau_m[h]);
            float bb = sigmf((d < 20) ? tau_n1[h] : tau_n2[h]);
            float diff = a - bb;
            if (fabsf(diff) < 1e-5f) { bb = a - 1e-5f; diff = 1e-5f; }
            const float w = (d < 20) ? W1[h * 20 + dm] : W2[h * 20 + dm];
            cw[h]  = Wo[h] * (1.f - a) * (1.f - bb) * w / diff;
            laG[h] = log2f(a);
            lbG[h] = log2f(bb);
        }
        __syncthreads();
        if (tid < 192) {
            const float fs1 = (float)(tid + 1);
            float acc = 0.f;
            for (int h = 0; h < 512; ++h)
                acc += cw[h] * (exp2f(fs1 * laG[h]) - exp2f(fs1 * lbG[h]));
            d_gT[d * L_ + tid] = acc;
        }
    } else {
        // c(t) = bo + sum_h [cst - A*a^{t+1} + B1*b1^{t+1} + B2*b2^{t+1}]
        __shared__ float As[512], B1s[512], B2s[512], cst[512],
                         laC[512], lb1C[512], lb2C[512];
        __shared__ float red[8][32];
        for (int i = 0; i < 2; ++i) {
            const int h = tid + 256 * i;
            const float a = sigmf(tau_m[h]);
            float b1c = sigmf(tau_n1[h]); float d1 = a - b1c;
            if (fabsf(d1) < 1e-5f) { b1c = a - 1e-5f; d1 = 1e-5f; }
            float b2c = sigmf(tau_n2[h]); float d2 = a - b2c;
            if (fabsf(d2) < 1e-5f) { b2c = a - 1e-5f; d2 = 1e-5f; }
            const float wv = Wo[h], bb1 = b1v[h], bb2 = b2v[h];
            As[h]  = wv * (bb1 * a * (1.f - b1c) / d1 + bb2 * a * (1.f - b2c) / d2);
            B1s[h] = wv * bb1 * b1c * (1.f - a) / d1;
            B2s[h] = wv * bb2 * b2c * (1.f - a) / d2;
            cst[h] = wv * (bb1 + bb2);
            laC[h] = log2f(a); lb1C[h] = log2f(b1c); lb2C[h] = log2f(b2c);
        }
        __syncthreads();
        const int tl = tid & 31;
        const int hc = tid >> 5;              // 8 h-chunks of 64
        const float ft1 = (float)((blk - 40) * 32 + tl + 1);
        float acc = 0.f;
        for (int hh = 0; hh < 64; ++hh) {
            const int h = hc * 64 + hh;
            acc += cst[h] - As[h] * exp2f(ft1 * laC[h])
                 + B1s[h] * exp2f(ft1 * lb1C[h])
                 + B2s[h] * exp2f(ft1 * lb2C[h]);
        }
        red[hc][tl] = acc;
        __syncthreads();
        if (tid < 32) {
            float s = bo[0];
#pragma unroll
            for (int c = 0; c < 8; ++c) s += red[c][tid];
            d_c[(blk - 40) * 32 + tid] = s;
        }
    }
}

// ---------------- main FIR kernel ----------------
// 512 blocks = 128 b x 4 t-tiles(512). 512 thr = 8 lg x 64 og.
// thread: outputs t0+8*og+{0..7}, lags [24*lg, 24*lg+24).
// Window: 31 dwords per 192 FMA. phi(t)=t+(t>>3), lane pitch 9 dwords
// (gcd(9,32)=1 -> 2 lanes/bank, free).
__global__ __launch_bounds__(512, 2) void fir_main(const float* __restrict__ x,
                                                   float* __restrict__ out)
{
    __shared__ __align__(16) float xw[20 * RS2];   // 63520 B -> 2 blocks/CU

    const int blk = blockIdx.x;
    const int b   = blk >> 2;
    const int t0  = (blk & 3) << 9;
    const int tid = threadIdx.x;
    const int og  = tid & 63;
    const int lg  = tid >> 6;                     // == wave id (uniform)
    const int lg_u = __builtin_amdgcn_readfirstlane(lg);

    const float* __restrict__ xb = x + (size_t)b * (T_ * DIN);

    float y[8];
#pragma unroll
    for (int r = 0; r < 8; ++r) y[r] = 0.f;

    // logical window base U0 = 8*og + 169 - 24*lg = 8K+1; phi(U0) = 9K+1
    const int K  = og + 21 - 3 * lg;
    const int AQ = 9 * K + 1;

    for (int dh = 0; dh < 2; ++dh) {
        __syncthreads();   // previous-phase readers done before overwrite
        // stage x[t0-192 .. t0+512) x d in [20dh,20dh+20) -> xw[dl][phi(tt)]
        for (int k = 0; k < 7; ++k) {
            const int phi = tid + 512 * k;
            if (phi < TT * 5) {
                const int tr = phi / 5, dq = phi - tr * 5;
                const int tg = t0 - L_ + tr;
                float4 v = make_float4(0.f, 0.f, 0.f, 0.f);
                if (tg >= 0)
                    v = *(const float4*)&xb[tg * DIN + dh * 20 + dq * 4];
                const int tph = tr + (tr >> 3);
                float* colp = &xw[(dq * 4) * RS2 + tph];
                colp[0]       = v.x;
                colp[RS2]     = v.y;
                colp[2 * RS2] = v.z;
                colp[3 * RS2] = v.w;
            }
        }
        __syncthreads();

        for (int dl = 0; dl < 20; ++dl) {
            const float* __restrict__ rowp = &xw[dl * RS2 + AQ];
            const float* __restrict__ gr = &d_gT[(dh * 20 + dl) * L_ + 24 * lg_u];
            float W[31];
#pragma unroll
            for (int m = 0; m < 31; ++m)
                W[m] = rowp[m + ((m + 1) >> 3)];  // imm offsets, lane pitch 9
#pragma unroll
            for (int j = 0; j < 24; ++j) {
                const float gj = gr[j];           // wave-uniform -> s_load
#pragma unroll
                for (int r = 0; r < 8; ++r)
                    y[r] = fmaf(gj, W[r + 23 - j], y[r]);
            }
        }
    }

    // reduce 8 lag-slice partials per output
    __syncthreads();
    if (lg > 0) {
        float* p = &xw[((lg - 1) * 64 + og) * 12];
        *(float4*)&p[0] = make_float4(y[0], y[1], y[2], y[3]);
        *(float4*)&p[4] = make_float4(y[4], y[5], y[6], y[7]);
    }
    __syncthreads();
    if (lg == 0) {
#pragma unroll
        for (int pw = 0; pw < 7; ++pw) {
            const float* p = &xw[(pw * 64 + og) * 12];
            float4 u0 = *(const float4*)&p[0];
            float4 u1 = *(const float4*)&p[4];
            y[0] += u0.x; y[1] += u0.y; y[2] += u0.z; y[3] += u0.w;
            y[4] += u1.x; y[5] += u1.y; y[6] += u1.z; y[7] += u1.w;
        }
        const float4 c0 = *(const float4*)&d_c[t0 + 8 * og];
        const float4 c1 = *(const float4*)&d_c[t0 + 8 * og + 4];
        float4 o0, o1;
        o0.x = sigmf(y[0] + c0.x); o0.y = sigmf(y[1] + c0.y);
        o0.z = sigmf(y[2] + c0.z); o0.w = sigmf(y[3] + c0.w);
        o1.x = sigmf(y[4] + c1.x); o1.y = sigmf(y[5] + c1.y);
        o1.z = sigmf(y[6] + c1.z); o1.w = sigmf(y[7] + c1.w);
        float* op = out + (size_t)b * T_ + t0 + 8 * og;
        *(float4*)&op[0] = o0;
        *(float4*)&op[4] = o1;
    }
}

extern "C" void kernel_launch(void* const* d_in, const int* in_sizes, int n_in,
                              void* d_out, int out_size, void* d_ws, size_t ws_size,
                              hipStream_t stream)
{
    const float* x      = (const float*)d_in[0];
    const float* W1     = (const float*)d_in[1];
    const float* b1     = (const float*)d_in[2];
    const float* W2     = (const float*)d_in[3];
    const float* b2     = (const float*)d_in[4];
    const float* Wo     = (const float*)d_in[5];
    const float* bo     = (const float*)d_in[6];
    const float* tau_m  = (const float*)d_in[7];
    const float* tau_n1 = (const float*)d_in[8];
    const float* tau_n2 = (const float*)d_in[9];

    hipLaunchKernelGGL(prepG, dim3(104), dim3(256), 0, stream,
                       W1, b1, W2, b2, Wo, bo, tau_m, tau_n1, tau_n2);
    hipLaunchKernelGGL(fir_main, dim3(512), dim3(512), 0, stream,
                       x, (float*)d_out);
}